// Round 3
// baseline (174.525 us; speedup 1.0000x reference)
//
#include <hip/hip_runtime.h>
#include <hip/hip_bf16.h>
#include <stdint.h>

// ---------------------------------------------------------------------------
// PoseFeatureExtractor fused kernel for MI355X (gfx950) — round 3
//   - phase 0 restructured: centered poses staged in LDS in two 34-frame
//     half-tiles (fp32, coalesced); root cancels => only per-frame scale kept
//   - packed bf16 converts (v_cvt_pk_bf16_f32), fast rcp/sqrt, nibble-packed
//     edge tables, jw in LDS
//   - LDS 52.5KB -> still 3 blocks/CU; W1/W2 B-frags via registers (unchanged)
// ---------------------------------------------------------------------------

#define S_    2048
#define MT_   64
#define HID_  256
#define OUT_  128

typedef __attribute__((ext_vector_type(8))) short   short8;   // bf16x8 MFMA frag
typedef __attribute__((ext_vector_type(4))) float   floatx4;  // fp32x4 MFMA acc

// edge tables packed as nibbles: c0[e] = (C0M>>4e)&15 ; c1[e] = ((C1M>>4e)&15)+1
#define C0M 0x0ECDB118675110ULL
#define C1M 0x0FDECBA9786540ULL

__device__ __forceinline__ unsigned short bf16_bits(float v) {
    union { float f; unsigned u; } x; x.f = v;
    unsigned r = x.u + 0x7fffu + ((x.u >> 16) & 1u);   // RNE
    return (unsigned short)(r >> 16);
}

__device__ __forceinline__ unsigned pkbf16(float a, float b) {
#if __has_builtin(__builtin_amdgcn_cvt_pk_bf16_f32)
    auto v = __builtin_amdgcn_cvt_pk_bf16_f32(a, b);   // RNE, 1 instr
    unsigned u; __builtin_memcpy(&u, &v, 4); return u;
#else
    return (unsigned)bf16_bits(a) | ((unsigned)bf16_bits(b) << 16);
#endif
}

// |err| <= 6.7e-5 abs (A&S 4.4.45) — far below bf16 feature quantization
__device__ __forceinline__ float facos(float x) {
    float ax = fabsf(x);
    float p = fmaf(ax, -0.0187293f, 0.0742610f);
    p = fmaf(ax, p, -0.2121144f);
    p = fmaf(ax, p, 1.5707288f);
    float r = __builtin_amdgcn_sqrtf(1.f - ax) * p;
    return x < 0.f ? 3.14159265358979f - r : r;
}

// --------------------------- prep kernel -----------------------------------
// Fold BN into W1/b1; pack W1 (K 300->320) and W2 into bf16 MFMA-B-fragment
// order (frag block = contiguous 1KB; lane l holds B[k=(l>>4)*8+j][n=l&15]).
// Coalesced reads (n fastest), scattered ushort writes (fire-and-forget).
__global__ void prep_kernel(const float* __restrict__ W1, const float* __restrict__ b1,
                            const float* __restrict__ gamma, const float* __restrict__ beta,
                            const float* __restrict__ rmean, const float* __restrict__ rvar,
                            const float* __restrict__ W2,
                            unsigned short* __restrict__ w1p,
                            unsigned short* __restrict__ w2p,
                            float* __restrict__ b1p) {
    int idx = blockIdx.x * 256 + threadIdx.x;
    if (idx < 81920) {                       // W1 folded + packed
        int k = idx >> 8, n = idx & 255;
        float a = gamma[n] * __builtin_amdgcn_rsqf(rvar[n] + 1e-5f);
        float v = (k < 300) ? W1[k * HID_ + n] * a : 0.f;
        int blk = (k >> 5) * 16 + (n >> 4);
        int off = blk * 512 + (((k >> 3) & 3) * 16 + (n & 15)) * 8 + (k & 7);
        w1p[off] = bf16_bits(v);
    } else if (idx < 114688) {               // W2 packed
        int i2 = idx - 81920;
        int k = i2 >> 7, n = i2 & 127;
        int blk = (k >> 5) * 8 + (n >> 4);
        int off = blk * 512 + (((k >> 3) & 3) * 16 + (n & 15)) * 8 + (k & 7);
        w2p[off] = bf16_bits(W2[k * OUT_ + n]);
    } else if (idx < 114944) {               // folded bias
        int n = idx - 114688;
        float a = gamma[n] * __builtin_amdgcn_rsqf(rvar[n] + 1e-5f);
        b1p[n] = fmaf(a, b1[n] - rmean[n], beta[n]);
    }
}

// --------------------------- main fused kernel ------------------------------
// LDS: feat 64 x 328 ushort (41984B; reused as hidden 64 x 264)
//      pbuf 34 x 76 fp32 centered poses (10336B), rsm/scale 34, jw 25
#define LDS_FEAT 0
#define LDS_PB   41984
#define LDS_RSM  (LDS_PB + 34 * 76 * 4)     // 52320
#define LDS_JW   (LDS_RSM + 34 * 4)         // 52456
#define LDS_TOT  (LDS_JW + 25 * 4 + 4)      // 52560 -> 3 blocks/CU

__global__ __launch_bounds__(256, 3) void pose_mlp(
    const float* __restrict__ poses,
    const unsigned short* __restrict__ w1p,
    const unsigned short* __restrict__ w2p,
    const float* __restrict__ b1p,
    const float* __restrict__ b2,
    const float* __restrict__ jw,
    float* __restrict__ out)
{
    __shared__ __align__(16) unsigned char smem[LDS_TOT];
    const int tid  = threadIdx.x;
    const int lane = tid & 63;
    const int wv   = tid >> 6;
    const int t0   = blockIdx.x * MT_;
    const int s0   = t0 & (S_ - 1);

    unsigned short* feat = (unsigned short*)(smem + LDS_FEAT);
    float*    pbuf = (float*)(smem + LDS_PB);
    unsigned* rsm  = (unsigned*)(smem + LDS_RSM);
    float*    scl  = (float*)rsm;
    float*    jwl  = (float*)(smem + LDS_JW);

    // early prefetch: phase-1 kc=0 B-frags (in flight across all of phase 0)
    short8 bw[4];
    #pragma unroll
    for (int ni = 0; ni < 4; ni++)
        bw[ni] = *(const short8*)(w1p + (unsigned)(wv * 4 + ni) * 512 + lane * 8);

    if (tid < 25) jwl[tid] = jw[tid];
    // zero constant-pad slots once: angle slots j>=13 (36) + K-pad 300..327 (28)
    for (int i = tid; i < MT_ * 64; i += 256) {
        int tt = i >> 6, z = i & 63;
        int k;
        if (z < 36) { int jj = z / 3; k = (13 + jj) * 12 + 9 + (z - jj * 3); }
        else        { k = 300 + z - 36; }
        feat[tt * 328 + k] = 0;
    }

    // ---------------- phase 0: two 34-frame half-tiles ----------------
    for (int h = 0; h < 2; h++) {
        int hb = t0 + 32 * h - 2;                    // global frame of f=0
        if (tid < 34) rsm[tid] = 0u;
        // (a) stage centered poses, coalesced (root cancels: row 0 -> 0)
        for (int i = tid; i < 34 * 75; i += 256) {
            int f = i / 75, r = i - f * 75;
            int g = hb + f; if (g < 0) g = 0;        // masked later
            const float* P = poses + (size_t)g * 75;
            pbuf[f * 76 + r] = P[r] - P[r - (r / 3) * 3];
        }
        __syncthreads();
        // (b) per-frame max dist^2 via LDS atomicMax (uint order == float order)
        for (int i = tid; i < 34 * 25; i += 256) {
            int f = i / 25, j = i - f * 25;
            const float* q = pbuf + f * 76 + j * 3;
            float d2 = fmaf(q[0], q[0], fmaf(q[1], q[1], q[2] * q[2]));
            atomicMax(&rsm[f], __float_as_uint(d2));
        }
        __syncthreads();
        // (c) scale = 1/(max_dist + 1e-8)
        if (tid < 34) {
            float m = __uint_as_float(rsm[tid]);
            scl[tid] = __builtin_amdgcn_rcpf(__builtin_amdgcn_sqrtf(m) + 1e-8f);
        }
        __syncthreads();
        // (d1) pos/vel/acc per (token, joint) — 800 items, all LDS-sourced
        for (int i = tid; i < 32 * 25; i += 256) {
            int tt = i / 25, j = i - tt * 25;
            int s  = s0 + 32 * h + tt;
            const float* pc = pbuf + (tt + 2) * 76 + j * 3;
            const float* pm = pc - 76;
            const float* pp = pc - 152;
            float sc = scl[tt + 2], sm = scl[tt + 1], sp = scl[tt];
            float cx = pc[0] * sc, cy = pc[1] * sc, cz = pc[2] * sc;
            float mx = pm[0] * sm, my = pm[1] * sm, mz = pm[2] * sm;
            float px = pp[0] * sp, py = pp[1] * sp, pz = pp[2] * sp;
            bool h1 = (s >= 1), h2 = (s >= 2);
            float vx = h1 ? cx - mx : 0.f, vy = h1 ? cy - my : 0.f, vz = h1 ? cz - mz : 0.f;
            float ux = h2 ? mx - px : 0.f, uy = h2 ? my - py : 0.f, uz = h2 ? mz - pz : 0.f;
            float qx = vx - ux, qy = vy - uy, qz = vz - uz;   // acc (s==1 -> vel)
            float w = jwl[j];
            unsigned base = (unsigned)(32 * h + tt) * 328 + j * 12;
            *(unsigned*)(feat + base)     = pkbf16(cx * w, cy * w);
            *(unsigned*)(feat + base + 2) = pkbf16(cz * w, vx * w);
            *(unsigned*)(feat + base + 4) = pkbf16(vy * w, vz * w);
            *(unsigned*)(feat + base + 6) = pkbf16(qx * w, qy * w);
            feat[base + 8] = bf16_bits(qz * w);
        }
        // (d2) joint angles per (token, edge) — 416 items
        // v/||v|| invariant to centering+positive scale -> use centered coords
        for (int i = tid; i < 32 * 13; i += 256) {
            int tt = i / 13, e = i - tt * 13;
            const float* pf = pbuf + (tt + 2) * 76;
            int a0 = (int)((C0M >> (4 * e)) & 15) * 3;
            int a1 = (((int)((C1M >> (4 * e)) & 15)) + 1) * 3;
            float vx = pf[a1] - pf[a0], vy = pf[a1+1] - pf[a0+1], vz = pf[a1+2] - pf[a0+2];
            float d  = fmaf(vx, vx, fmaf(vy, vy, vz * vz));
            float inv = __builtin_amdgcn_rcpf(fmaxf(__builtin_amdgcn_sqrtf(d), 1e-12f));
            float w = jwl[e];
            float A0 = facos(fminf(fmaxf(vx * inv, -1.f), 1.f)) * w;
            float A1 = facos(fminf(fmaxf(vy * inv, -1.f), 1.f)) * w;
            float A2 = facos(fminf(fmaxf(vz * inv, -1.f), 1.f)) * w;
            unsigned base = (unsigned)(32 * h + tt) * 328 + e * 12 + 9;
            feat[base] = bf16_bits(A0);
            *(unsigned*)(feat + base + 1) = pkbf16(A1, A2);
        }
        __syncthreads();   // h=0: pbuf free for h=1; h=1: feat complete
    }

    // ---------------- phase 1: hidden = relu(feat @ W1' + b1') ----------------
    floatx4 acc[4][4];
    #pragma unroll
    for (int mi = 0; mi < 4; mi++)
        #pragma unroll
        for (int ni = 0; ni < 4; ni++) acc[mi][ni] = (floatx4){0.f, 0.f, 0.f, 0.f};

    #pragma unroll 1
    for (int kc = 0; kc < 10; kc++) {
        short8 bn[4];
        if (kc < 9) {
            #pragma unroll
            for (int ni = 0; ni < 4; ni++)
                bn[ni] = *(const short8*)(w1p + (unsigned)((kc + 1) * 16 + wv * 4 + ni) * 512 + lane * 8);
        }
        short8 af[4];
        #pragma unroll
        for (int mi = 0; mi < 4; mi++)   // A: row=(l&15)+16mi, k=kc*32+(l>>4)*8
            af[mi] = *(const short8*)(feat + (mi * 16 + (lane & 15)) * 328 + kc * 32 + (lane >> 4) * 8);
        #pragma unroll
        for (int mi = 0; mi < 4; mi++)
            #pragma unroll
            for (int ni = 0; ni < 4; ni++)
                acc[mi][ni] = __builtin_amdgcn_mfma_f32_16x16x32_bf16(
                    af[mi], bw[ni], acc[mi][ni], 0, 0, 0);
        if (kc < 9) {
            #pragma unroll
            for (int ni = 0; ni < 4; ni++) bw[ni] = bn[ni];
        }
    }

    // preload W2 kc=0 frags before the barrier (independent of LDS)
    short8 bw2[2];
    #pragma unroll
    for (int ni = 0; ni < 2; ni++)
        bw2[ni] = *(const short8*)(w2p + (unsigned)(wv * 2 + ni) * 512 + lane * 8);

    __syncthreads();   // all waves done reading feat

    unsigned short* hid = feat;                            // reuse, stride 264
    float bv[4];
    #pragma unroll
    for (int ni = 0; ni < 4; ni++) bv[ni] = b1p[wv * 64 + ni * 16 + (lane & 15)];
    #pragma unroll
    for (int mi = 0; mi < 4; mi++)
        #pragma unroll
        for (int ni = 0; ni < 4; ni++)
            #pragma unroll
            for (int r = 0; r < 4; r++) {
                float v = fmaxf(acc[mi][ni][r] + bv[ni], 0.f);
                int m   = mi * 16 + (lane >> 4) * 4 + r;   // C/D: row=(l>>4)*4+r
                int col = wv * 64 + ni * 16 + (lane & 15); //      col=l&15
                hid[m * 264 + col] = bf16_bits(v);
            }
    __syncthreads();   // hid visible

    // ---------------- phase 2: out = hidden @ W2 + b2 ----------------
    floatx4 acc2[4][2];
    #pragma unroll
    for (int mi = 0; mi < 4; mi++)
        #pragma unroll
        for (int ni = 0; ni < 2; ni++) acc2[mi][ni] = (floatx4){0.f, 0.f, 0.f, 0.f};

    #pragma unroll 1
    for (int kc = 0; kc < 8; kc++) {
        short8 bn2[2];
        if (kc < 7) {
            #pragma unroll
            for (int ni = 0; ni < 2; ni++)
                bn2[ni] = *(const short8*)(w2p + (unsigned)((kc + 1) * 8 + wv * 2 + ni) * 512 + lane * 8);
        }
        short8 af[4];
        #pragma unroll
        for (int mi = 0; mi < 4; mi++)
            af[mi] = *(const short8*)(hid + (mi * 16 + (lane & 15)) * 264 + kc * 32 + (lane >> 4) * 8);
        #pragma unroll
        for (int mi = 0; mi < 4; mi++)
            #pragma unroll
            for (int ni = 0; ni < 2; ni++)
                acc2[mi][ni] = __builtin_amdgcn_mfma_f32_16x16x32_bf16(
                    af[mi], bw2[ni], acc2[mi][ni], 0, 0, 0);
        if (kc < 7) {
            #pragma unroll
            for (int ni = 0; ni < 2; ni++) bw2[ni] = bn2[ni];
        }
    }

    float c2[2];
    #pragma unroll
    for (int ni = 0; ni < 2; ni++) c2[ni] = b2[wv * 32 + ni * 16 + (lane & 15)];
    #pragma unroll
    for (int mi = 0; mi < 4; mi++)
        #pragma unroll
        for (int ni = 0; ni < 2; ni++)
            #pragma unroll
            for (int r = 0; r < 4; r++) {
                int m   = mi * 16 + (lane >> 4) * 4 + r;
                int col = wv * 32 + ni * 16 + (lane & 15);
                out[(size_t)(t0 + m) * OUT_ + col] = acc2[mi][ni][r] + c2[ni];
            }
}

// --------------------------- launch -----------------------------------------
extern "C" void kernel_launch(void* const* d_in, const int* in_sizes, int n_in,
                              void* d_out, int out_size, void* d_ws, size_t ws_size,
                              hipStream_t stream) {
    (void)in_sizes; (void)n_in; (void)out_size; (void)ws_size;
    const float* poses = (const float*)d_in[0];
    const float* W1    = (const float*)d_in[1];
    const float* b1    = (const float*)d_in[2];
    const float* gamma = (const float*)d_in[3];
    const float* beta  = (const float*)d_in[4];
    const float* rmean = (const float*)d_in[5];
    const float* rvar  = (const float*)d_in[6];
    const float* W2    = (const float*)d_in[7];
    const float* b2    = (const float*)d_in[8];
    const float* jw    = (const float*)d_in[9];

    unsigned short* w1p = (unsigned short*)d_ws;                 // 320*256 bf16
    unsigned short* w2p = w1p + 320 * HID_;                      // 256*128 bf16
    float* b1p = (float*)((char*)d_ws + (320 * HID_ + HID_ * OUT_) * 2);

    prep_kernel<<<449, 256, 0, stream>>>(W1, b1, gamma, beta, rmean, rvar, W2,
                                         w1p, w2p, b1p);
    pose_mlp<<<2048, 256, 0, stream>>>(poses, w1p, w2p, b1p, b2, jw, (float*)d_out);
}

// Round 4
// 144.409 us; speedup vs baseline: 1.2085x; 1.2085x over previous
//
#include <hip/hip_runtime.h>
#include <hip/hip_bf16.h>
#include <stdint.h>

// ---------------------------------------------------------------------------
// PoseFeatureExtractor fused kernel for MI355X (gfx950) — round 4
//   - r2 structure (global-read phase 0, register W-streaming) restored
//   - 512 threads/block, MT=64: same LDS -> 3 blocks/CU but 24 waves/CU
//   - LDS atomicMax replaced by two-stage contention-free max reduction
//   - r3's cheap math kept: pkbf16, fast acos, rcp/sqrt, nibble edge tables
// ---------------------------------------------------------------------------

#define S_    2048
#define MT_   64
#define TPB   512
#define HID_  256
#define OUT_  128

typedef __attribute__((ext_vector_type(8))) short   short8;   // bf16x8 MFMA frag
typedef __attribute__((ext_vector_type(4))) float   floatx4;  // fp32x4 MFMA acc

// edge tables packed as nibbles: c0[e] = (C0M>>4e)&15 ; c1[e] = ((C1M>>4e)&15)+1
#define C0M 0x0ECDB118675110ULL
#define C1M 0x0FDECBA9786540ULL

__device__ __forceinline__ unsigned short bf16_bits(float v) {
    union { float f; unsigned u; } x; x.f = v;
    unsigned r = x.u + 0x7fffu + ((x.u >> 16) & 1u);   // RNE
    return (unsigned short)(r >> 16);
}

__device__ __forceinline__ unsigned pkbf16(float a, float b) {
#if __has_builtin(__builtin_amdgcn_cvt_pk_bf16_f32)
    auto v = __builtin_amdgcn_cvt_pk_bf16_f32(a, b);   // RNE, 1 instr
    unsigned u; __builtin_memcpy(&u, &v, 4); return u;
#else
    return (unsigned)bf16_bits(a) | ((unsigned)bf16_bits(b) << 16);
#endif
}

// |err| <= 6.7e-5 abs (A&S 4.4.45) — far below bf16 feature quantization
__device__ __forceinline__ float facos(float x) {
    float ax = fabsf(x);
    float p = fmaf(ax, -0.0187293f, 0.0742610f);
    p = fmaf(ax, p, -0.2121144f);
    p = fmaf(ax, p, 1.5707288f);
    float r = __builtin_amdgcn_sqrtf(1.f - ax) * p;
    return x < 0.f ? 3.14159265358979f - r : r;
}

// --------------------------- prep kernel -----------------------------------
// Fold BN into W1/b1; pack W1 (K 300->320) and W2 into bf16 MFMA-B-fragment
// order (frag block = contiguous 1KB; lane l holds B[k=(l>>4)*8+j][n=l&15]).
__global__ void prep_kernel(const float* __restrict__ W1, const float* __restrict__ b1,
                            const float* __restrict__ gamma, const float* __restrict__ beta,
                            const float* __restrict__ rmean, const float* __restrict__ rvar,
                            const float* __restrict__ W2,
                            unsigned short* __restrict__ w1p,
                            unsigned short* __restrict__ w2p,
                            float* __restrict__ b1p) {
    int idx = blockIdx.x * 256 + threadIdx.x;
    if (idx < 81920) {                       // W1 folded + packed
        int k = idx >> 8, n = idx & 255;
        float a = gamma[n] * __builtin_amdgcn_rsqf(rvar[n] + 1e-5f);
        float v = (k < 300) ? W1[k * HID_ + n] * a : 0.f;
        int blk = (k >> 5) * 16 + (n >> 4);
        int off = blk * 512 + (((k >> 3) & 3) * 16 + (n & 15)) * 8 + (k & 7);
        w1p[off] = bf16_bits(v);
    } else if (idx < 114688) {               // W2 packed
        int i2 = idx - 81920;
        int k = i2 >> 7, n = i2 & 127;
        int blk = (k >> 5) * 8 + (n >> 4);
        int off = blk * 512 + (((k >> 3) & 3) * 16 + (n & 15)) * 8 + (k & 7);
        w2p[off] = bf16_bits(W2[k * OUT_ + n]);
    } else if (idx < 114944) {               // folded bias
        int n = idx - 114688;
        float a = gamma[n] * __builtin_amdgcn_rsqf(rvar[n] + 1e-5f);
        b1p[n] = fmaf(a, b1[n] - rmean[n], beta[n]);
    }
}

// --------------------------- main fused kernel ------------------------------
// LDS: feat 64 x 328 ushort (41984B; reused as hidden 64 x 264)
//      pm[330] partial max-d2, rs[66] float4 (root.xyz, scale), jw[25]
#define LDS_FEAT 0
#define LDS_PM   41984
#define LDS_RS   43312                       // 16B aligned
#define LDS_JW   (LDS_RS + 66 * 16)          // 44368
#define LDS_TOT  (LDS_JW + 25 * 4 + 12)      // 44480 -> 3 blocks/CU, 24 waves

__global__ __launch_bounds__(TPB, 6) void pose_mlp(
    const float* __restrict__ poses,
    const unsigned short* __restrict__ w1p,
    const unsigned short* __restrict__ w2p,
    const float* __restrict__ b1p,
    const float* __restrict__ b2,
    const float* __restrict__ jw,
    float* __restrict__ out)
{
    __shared__ __align__(16) unsigned char smem[LDS_TOT];
    const int tid  = threadIdx.x;
    const int lane = tid & 63;
    const int wv   = tid >> 6;               // 0..7
    const int t0   = blockIdx.x * MT_;
    const int s0   = t0 & (S_ - 1);

    unsigned short* feat = (unsigned short*)(smem + LDS_FEAT);
    float*  pm  = (float*)(smem + LDS_PM);
    float4* rs  = (float4*)(smem + LDS_RS);
    float*  jwl = (float*)(smem + LDS_JW);

    // early prefetch: phase-1 kc=0 B-frags (this wave's 2 n-tiles)
    short8 bw[2];
    #pragma unroll
    for (int ni = 0; ni < 2; ni++)
        bw[ni] = *(const short8*)(w1p + (unsigned)(wv * 2 + ni) * 512 + lane * 8);

    if (tid < 25) jwl[tid] = jw[tid];
    // zero constant-pad slots: angle slots j>=13 (36) + K-pad 300..327 (28)
    for (int i = tid; i < MT_ * 64; i += TPB) {
        int tt = i >> 6, z = i & 63;
        int k;
        if (z < 36) { int jj = z / 3; k = (13 + jj) * 12 + 9 + (z - jj * 3); }
        else        { k = 300 + z - 36; }
        feat[tt * 328 + k] = 0;
    }

    // ---- phase 0a: partial max-d2 per (frame, 5-joint group) — no atomics ----
    for (int i = tid; i < 66 * 5; i += TPB) {
        int f = i / 5, grp = i - f * 5;
        int g = t0 - 2 + f; if (g < 0) g = 0;        // clamped; masked later
        const float* P = poses + (size_t)g * 75;
        float r0 = P[0], r1 = P[1], r2 = P[2];
        float m2 = 0.f;
        #pragma unroll
        for (int jj = 0; jj < 5; jj++) {
            int j = grp * 5 + jj;
            float dx = P[j*3]   - r0;
            float dy = P[j*3+1] - r1;
            float dz = P[j*3+2] - r2;
            m2 = fmaxf(m2, fmaf(dx, dx, fmaf(dy, dy, dz * dz)));
        }
        pm[i] = m2;
    }
    __syncthreads();
    // ---- phase 0b: final reduce -> root + scale per frame ----
    if (tid < 66) {
        int g = t0 - 2 + tid; if (g < 0) g = 0;
        const float* P = poses + (size_t)g * 75;
        const float* q = pm + tid * 5;
        float m2 = fmaxf(fmaxf(fmaxf(q[0], q[1]), fmaxf(q[2], q[3])), q[4]);
        float sc = __builtin_amdgcn_rcpf(__builtin_amdgcn_sqrtf(m2) + 1e-8f);
        rs[tid] = make_float4(P[0], P[1], P[2], sc);
    }
    __syncthreads();

    // ---- phase 0c: pos/vel/acc per (token, joint) — 1600 items ----
    for (int i = tid; i < MT_ * 25; i += TPB) {
        int tt = i / 25, j = i - tt * 25;
        int s  = s0 + tt;
        int g  = t0 + tt;
        int g1 = g - 1 < 0 ? 0 : g - 1;
        int g2 = g - 2 < 0 ? 0 : g - 2;
        const float* Pc = poses + (size_t)g  * 75 + j * 3;
        const float* P1 = poses + (size_t)g1 * 75 + j * 3;
        const float* P2 = poses + (size_t)g2 * 75 + j * 3;
        float4 rc = rs[tt + 2], rm = rs[tt + 1], rp = rs[tt];
        float cx = (Pc[0] - rc.x) * rc.w, cy = (Pc[1] - rc.y) * rc.w, cz = (Pc[2] - rc.z) * rc.w;
        float mx = (P1[0] - rm.x) * rm.w, my = (P1[1] - rm.y) * rm.w, mz = (P1[2] - rm.z) * rm.w;
        float px = (P2[0] - rp.x) * rp.w, py = (P2[1] - rp.y) * rp.w, pz = (P2[2] - rp.z) * rp.w;
        bool h1 = (s >= 1), h2 = (s >= 2);
        float vx = h1 ? cx - mx : 0.f, vy = h1 ? cy - my : 0.f, vz = h1 ? cz - mz : 0.f;
        float ux = h2 ? mx - px : 0.f, uy = h2 ? my - py : 0.f, uz = h2 ? mz - pz : 0.f;
        float qx = vx - ux, qy = vy - uy, qz = vz - uz;   // acc (s==1 -> vel)
        float w = jwl[j];
        unsigned base = (unsigned)tt * 328 + j * 12;      // even -> dword aligned
        *(unsigned*)(feat + base)     = pkbf16(cx * w, cy * w);
        *(unsigned*)(feat + base + 2) = pkbf16(cz * w, vx * w);
        *(unsigned*)(feat + base + 4) = pkbf16(vy * w, vz * w);
        *(unsigned*)(feat + base + 6) = pkbf16(qx * w, qy * w);
        feat[base + 8] = bf16_bits(qz * w);
    }

    // ---- phase 0d: joint angles per (token, edge) — 832 items ----
    // v/||v|| invariant to centering + positive scale -> raw global coords
    for (int i = tid; i < MT_ * 13; i += TPB) {
        int tt = i / 13, e = i - tt * 13;
        int g  = t0 + tt;
        const float* P = poses + (size_t)g * 75;
        int a0 = (int)((C0M >> (4 * e)) & 15) * 3;
        int a1 = (((int)((C1M >> (4 * e)) & 15)) + 1) * 3;
        float vx = P[a1] - P[a0], vy = P[a1+1] - P[a0+1], vz = P[a1+2] - P[a0+2];
        float d  = fmaf(vx, vx, fmaf(vy, vy, vz * vz));
        float inv = __builtin_amdgcn_rcpf(fmaxf(__builtin_amdgcn_sqrtf(d), 1e-12f));
        float w = jwl[e];
        float A0 = facos(fminf(fmaxf(vx * inv, -1.f), 1.f)) * w;
        float A1 = facos(fminf(fmaxf(vy * inv, -1.f), 1.f)) * w;
        float A2 = facos(fminf(fmaxf(vz * inv, -1.f), 1.f)) * w;
        unsigned base = (unsigned)tt * 328 + e * 12 + 9;  // odd
        feat[base] = bf16_bits(A0);
        *(unsigned*)(feat + base + 1) = pkbf16(A1, A2);
    }
    __syncthreads();

    // ---- phase 1: hidden = relu(feat @ W1' + b1'); wave wv owns n-tiles 2wv,2wv+1
    floatx4 acc[4][2];
    #pragma unroll
    for (int mi = 0; mi < 4; mi++)
        #pragma unroll
        for (int ni = 0; ni < 2; ni++) acc[mi][ni] = (floatx4){0.f, 0.f, 0.f, 0.f};

    #pragma unroll 1
    for (int kc = 0; kc < 10; kc++) {
        short8 bn[2];
        if (kc < 9) {
            #pragma unroll
            for (int ni = 0; ni < 2; ni++)
                bn[ni] = *(const short8*)(w1p + (unsigned)((kc + 1) * 16 + wv * 2 + ni) * 512 + lane * 8);
        }
        short8 af[4];
        #pragma unroll
        for (int mi = 0; mi < 4; mi++)   // A: row=(l&15)+16mi, k=kc*32+(l>>4)*8
            af[mi] = *(const short8*)(feat + (mi * 16 + (lane & 15)) * 328 + kc * 32 + (lane >> 4) * 8);
        #pragma unroll
        for (int mi = 0; mi < 4; mi++)
            #pragma unroll
            for (int ni = 0; ni < 2; ni++)
                acc[mi][ni] = __builtin_amdgcn_mfma_f32_16x16x32_bf16(
                    af[mi], bw[ni], acc[mi][ni], 0, 0, 0);
        if (kc < 9) {
            #pragma unroll
            for (int ni = 0; ni < 2; ni++) bw[ni] = bn[ni];
        }
    }

    // preload W2 kc=0 frag (this wave's n-tile), independent of LDS
    short8 bw2 = *(const short8*)(w2p + (unsigned)wv * 512 + lane * 8);

    __syncthreads();   // all waves done reading feat

    unsigned short* hid = feat;                            // reuse, stride 264
    float bv[2];
    #pragma unroll
    for (int ni = 0; ni < 2; ni++) bv[ni] = b1p[wv * 32 + ni * 16 + (lane & 15)];
    #pragma unroll
    for (int mi = 0; mi < 4; mi++)
        #pragma unroll
        for (int ni = 0; ni < 2; ni++)
            #pragma unroll
            for (int r = 0; r < 4; r++) {
                float v = fmaxf(acc[mi][ni][r] + bv[ni], 0.f);
                int m   = mi * 16 + (lane >> 4) * 4 + r;   // C/D: row=(l>>4)*4+r
                int col = wv * 32 + ni * 16 + (lane & 15); //      col=l&15
                hid[m * 264 + col] = bf16_bits(v);
            }
    __syncthreads();   // hid visible

    // ---- phase 2: out = hidden @ W2 + b2; wave wv owns n-tile wv ----
    floatx4 acc2[4];
    #pragma unroll
    for (int mi = 0; mi < 4; mi++) acc2[mi] = (floatx4){0.f, 0.f, 0.f, 0.f};

    #pragma unroll 1
    for (int kc = 0; kc < 8; kc++) {
        short8 bn2;
        if (kc < 7)
            bn2 = *(const short8*)(w2p + (unsigned)((kc + 1) * 8 + wv) * 512 + lane * 8);
        short8 af[4];
        #pragma unroll
        for (int mi = 0; mi < 4; mi++)
            af[mi] = *(const short8*)(hid + (mi * 16 + (lane & 15)) * 264 + kc * 32 + (lane >> 4) * 8);
        #pragma unroll
        for (int mi = 0; mi < 4; mi++)
            acc2[mi] = __builtin_amdgcn_mfma_f32_16x16x32_bf16(
                af[mi], bw2, acc2[mi], 0, 0, 0);
        if (kc < 7) bw2 = bn2;
    }

    float c2 = b2[wv * 16 + (lane & 15)];
    #pragma unroll
    for (int mi = 0; mi < 4; mi++)
        #pragma unroll
        for (int r = 0; r < 4; r++) {
            int m   = mi * 16 + (lane >> 4) * 4 + r;
            int col = wv * 16 + (lane & 15);
            out[(size_t)(t0 + m) * OUT_ + col] = acc2[mi][r] + c2;
        }
}

// --------------------------- launch -----------------------------------------
extern "C" void kernel_launch(void* const* d_in, const int* in_sizes, int n_in,
                              void* d_out, int out_size, void* d_ws, size_t ws_size,
                              hipStream_t stream) {
    (void)in_sizes; (void)n_in; (void)out_size; (void)ws_size;
    const float* poses = (const float*)d_in[0];
    const float* W1    = (const float*)d_in[1];
    const float* b1    = (const float*)d_in[2];
    const float* gamma = (const float*)d_in[3];
    const float* beta  = (const float*)d_in[4];
    const float* rmean = (const float*)d_in[5];
    const float* rvar  = (const float*)d_in[6];
    const float* W2    = (const float*)d_in[7];
    const float* b2    = (const float*)d_in[8];
    const float* jw    = (const float*)d_in[9];

    unsigned short* w1p = (unsigned short*)d_ws;                 // 320*256 bf16
    unsigned short* w2p = w1p + 320 * HID_;                      // 256*128 bf16
    float* b1p = (float*)((char*)d_ws + (320 * HID_ + HID_ * OUT_) * 2);

    prep_kernel<<<449, 256, 0, stream>>>(W1, b1, gamma, beta, rmean, rvar, W2,
                                         w1p, w2p, b1p);
    pose_mlp<<<2048, TPB, 0, stream>>>(poses, w1p, w2p, b1p, b2, jw, (float*)d_out);
}